// Round 19
// baseline (73.156 us; speedup 1.0000x reference)
//
#include <hip/hip_runtime.h>

namespace {

constexpr int NS = 256;      // samples
constexpr int MP = 128;      // patches
constexpr int TSTEPS = 200;  // timesteps
constexpr int BLK = 512;     // 8 waves -> 2 waves/SIMD (proven optimum)

typedef _Float16 half8 __attribute__((ext_vector_type(8)));
typedef __fp16 h8v __attribute__((ext_vector_type(8)));
typedef float f32x4 __attribute__((ext_vector_type(4)));

__device__ __forceinline__ float4 ldg4(const float* p) {
  return *reinterpret_cast<const float4*>(p);
}
__device__ __forceinline__ float clamp01(float v) {
  return fminf(fmaxf(v, 0.0f), 1.0f);
}
// LDS-visibility barrier that does NOT drain vmcnt (stores stay in flight).
__device__ __forceinline__ void step_barrier() {
  asm volatile("s_waitcnt lgkmcnt(0)" ::: "memory");
  __builtin_amdgcn_s_barrier();
  asm volatile("" ::: "memory");
}
// pack two f32 -> f16x2 (RTZ)
__device__ __forceinline__ unsigned pkrtz(float a, float b) {
  typedef __fp16 h2v __attribute__((ext_vector_type(2)));
  h2v r = __builtin_amdgcn_cvt_pkrtz(a, b);
  return __builtin_bit_cast(unsigned, r);
}
// elementwise f16x8 multiply (4x v_pk_mul_f16)
__device__ __forceinline__ uint4 pkmul4(uint4 a, uint4 b) {
  h8v x = __builtin_bit_cast(h8v, a);
  h8v y = __builtin_bit_cast(h8v, b);
  h8v z = x * y;
  return __builtin_bit_cast(uint4, z);
}
// rotate-add within 16-lane DPP row: 0x121/0x122/0x124/0x128 = ror 1/2/4/8
template <int CTRL>
__device__ __forceinline__ float dpp_radd(float x) {
  int yi = __builtin_amdgcn_update_dpp(0, __float_as_int(x), CTRL, 0xF, 0xF, true);
  return x + __int_as_float(yi);
}
// fetch value from lane^1 (quad_perm [1,0,3,2])
__device__ __forceinline__ float dpp_xor1(float x) {
  int yi = __builtin_amdgcn_update_dpp(0, __float_as_int(x), 0xB1, 0xF, 0xF, true);
  return __int_as_float(yi);
}
// Swizzled uint4 (8 f16) index into f16 Q: 16 quads/row, XOR row-octet
__device__ __forceinline__ int qidx16(int row, int ch) {
  return (row << 4) + (ch ^ ((row >> 3) & 7));
}
__device__ __forceinline__ half8 h8(uint4 v) {
  return __builtin_bit_cast(half8, v);
}

__global__ __launch_bounds__(BLK, 2)
void sir_meta_kernel(const float* __restrict__ Rg,
                     const float* __restrict__ Tg,
                     const float* __restrict__ rho0g,
                     const float* __restrict__ betag,
                     float* __restrict__ outg)
{
  __shared__ __align__(16) float rs[MP];          // 1/rowsum (f32 exact)
  __shared__ __align__(16) unsigned binv16[64];   // beta/neff as f16 pairs
  __shared__ __align__(16) float scr[BLK];
  __shared__ __align__(16) unsigned xh[2][64];    // x as f16 pairs, dbuffered
  __shared__ __align__(16) uint4 q16[MP * 16];    // RAW R in f16 pairs (32KB)
  __shared__ __align__(16) uint4 gh[MP * 16];     // G in f16 pairs (8KB)

  const int tid = threadIdx.x;
  const int n = blockIdx.x;
  const float* __restrict__ Rn = Rg + (size_t)n * MP * MP;

  // ---- S1+S3a fused: stage RAW R as f16 (swizzled) AND row sums -> rs ----
  {
    #pragma unroll
    for (int u = 0; u < 4; ++u) {
      const int fi8 = u * BLK + tid;
      const int r = fi8 >> 4, c8 = fi8 & 15;
      float4 lo = ldg4(Rn + r * MP + c8 * 8);
      float4 hi = ldg4(Rn + r * MP + c8 * 8 + 4);
      uint4 w;
      w.x = pkrtz(lo.x, lo.y);
      w.y = pkrtz(lo.z, lo.w);
      w.z = pkrtz(hi.x, hi.y);
      w.w = pkrtz(hi.z, hi.w);
      q16[qidx16(r, c8)] = w;
      float p = ((lo.x + lo.y) + (lo.z + lo.w)) + ((hi.x + hi.y) + (hi.z + hi.w));
      p = dpp_radd<0x121>(p);
      p = dpp_radd<0x122>(p);
      p = dpp_radd<0x124>(p);
      p = dpp_radd<0x128>(p);
      if ((tid & 15) == 0) rs[r] = 1.0f / p;
    }
  }
  __syncthreads();

  // ---- S2: neff[c] = sum_i Rraw[i][c]*rs[i] (global coalesced, L2-hot) ----
  {
    const int c = tid & 127;
    const int h = tid >> 7;
    float a = 0.0f;
    #pragma unroll 8
    for (int i = 0; i < 32; ++i) {
      const int ig = h * 32 + i;
      a = fmaf(Rn[ig * MP + c], rs[ig], a);
    }
    scr[tid] = a;
  }
  __syncthreads();
  // binv16 pack directly from scr: lane t handles columns 2t, 2t+1
  if (tid < 64) {
    const float beta = betag[n];
    const int c0 = 2 * tid;
    const float s0 = ((scr[c0] + scr[c0 + 128]) + (scr[c0 + 256] + scr[c0 + 384]));
    const float s1 = ((scr[c0 + 1] + scr[c0 + 129]) + (scr[c0 + 257] + scr[c0 + 385]));
    binv16[tid] = pkrtz(beta / s0, beta / s1);
  }
  // initial x as f16 pairs (independent of binv; same barrier covers both)
  if (tid >= 64 && tid < 128) {
    const int t = tid - 64;
    const float* xp = rho0g + ((size_t)n * MP + 2 * t) * 3;
    xh[0][t] = pkrtz(xp[0], xp[3]);
  }
  __syncthreads();

  // ---- S3b: MFMA GEMM. Wave J computes G tiles (I=0..7, J). ----
  {
    const int J = tid >> 6;
    const int l = tid & 63;
    const int col = l & 15;
    const int kg = l >> 4;
    const uint4* bnv4 = reinterpret_cast<const uint4*>(binv16);
    uint4 bfj[4];
    #pragma unroll
    for (int c = 0; c < 4; ++c)
      bfj[c] = pkmul4(q16[qidx16(16 * J + col, 4 * c + kg)], bnv4[4 * c + kg]);
    const float rscol = rs[16 * J + col];
    unsigned* ghu = reinterpret_cast<unsigned*>(gh);
    #pragma unroll
    for (int I = 0; I < 8; ++I) {
      const uint4 af0 = q16[qidx16(16 * I + col, 0 + kg)];
      const uint4 af1 = q16[qidx16(16 * I + col, 4 + kg)];
      const uint4 af2 = q16[qidx16(16 * I + col, 8 + kg)];
      const uint4 af3 = q16[qidx16(16 * I + col, 12 + kg)];
      f32x4 a = {0.f, 0.f, 0.f, 0.f};
      a = __builtin_amdgcn_mfma_f32_16x16x32_f16(h8(af0), h8(bfj[0]), a, 0, 0, 0);
      a = __builtin_amdgcn_mfma_f32_16x16x32_f16(h8(af1), h8(bfj[1]), a, 0, 0, 0);
      a = __builtin_amdgcn_mfma_f32_16x16x32_f16(h8(af2), h8(bfj[2]), a, 0, 0, 0);
      a = __builtin_amdgcn_mfma_f32_16x16x32_f16(h8(af3), h8(bfj[3]), a, 0, 0, 0);
      #pragma unroll
      for (int r = 0; r < 4; ++r) {
        const int ROW = 16 * I + 4 * kg + r;
        const float val = a[r] * rs[ROW] * rscol;
        const float nb = dpp_xor1(val);            // neighbor col's scaled val
        if ((col & 1) == 0)
          ghu[ROW * 64 + 8 * J + (col >> 1)] = pkrtz(val, nb);
      }
    }
  }
  __syncthreads();

  // ---- R14 loop: wave w owns G rows [16w..16w+16) ----
  const int w = tid >> 6;
  const int l = tid & 63;
  const int col = l & 15;
  const int kg = l >> 4;
  const int jrow = 16 * w + 4 * kg + col;   // this lane's state row (col<4)
  const bool writer = (col < 4);

  uint4 af0 = gh[(16 * w + col) * 16 + 0 + kg];
  uint4 af1 = gh[(16 * w + col) * 16 + 4 + kg];
  uint4 af2 = gh[(16 * w + col) * 16 + 8 + kg];
  uint4 af3 = gh[(16 * w + col) * 16 + 12 + kg];

  const float* Tn = Tg + n * 9;
  const float T00 = Tn[0], T01 = Tn[1], T02 = Tn[2];
  const float T10 = Tn[3], T11 = Tn[4], T12 = Tn[5];
  const float T20 = Tn[6], T21 = Tn[7], T22 = Tn[8];

  float r0 = 0.f, r1 = 0.f, r2 = 0.f;
  if (writer) {
    const float* rp = rho0g + ((size_t)n * MP + jrow) * 3;
    r0 = rp[0]; r1 = rp[1]; r2 = rp[2];
  }

  float4* outp = reinterpret_cast<float4*>(outg) + (size_t)n * TSTEPS * MP + jrow;
  const bool xwriter = writer && ((col & 1) == 0);
  const int xslot = jrow >> 1;              // valid when col even

  for (int s = 0; s < TSTEPS; ++s) {
    // chain head: 4 broadcast uint4 x-reads (4 distinct addrs/wave)
    const uint4* xq4 = reinterpret_cast<const uint4*>(&xh[s & 1][0]);
    const uint4 b0 = xq4[kg];
    const uint4 b1 = xq4[4 + kg];
    const uint4 b2 = xq4[8 + kg];
    const uint4 b3 = xq4[12 + kg];

    // off-chain: emit pre-update state (coalesced 16-lane store per wave)
    const float S = 1.0f - ((r0 + r1) + r2);
    if (writer) *outp = make_float4(S, r0, r1, r2);
    outp += MP;

    // two 2-deep MFMA chains under raised priority (T5: role-split waves)
    __builtin_amdgcn_s_setprio(1);
    f32x4 accA = {0.f, 0.f, 0.f, 0.f};
    f32x4 accB = {0.f, 0.f, 0.f, 0.f};
    accA = __builtin_amdgcn_mfma_f32_16x16x32_f16(h8(af0), h8(b0), accA, 0, 0, 0);
    accB = __builtin_amdgcn_mfma_f32_16x16x32_f16(h8(af1), h8(b1), accB, 0, 0, 0);
    accA = __builtin_amdgcn_mfma_f32_16x16x32_f16(h8(af2), h8(b2), accA, 0, 0, 0);
    accB = __builtin_amdgcn_mfma_f32_16x16x32_f16(h8(af3), h8(b3), accB, 0, 0, 0);
    __builtin_amdgcn_s_setprio(0);

    // static select of this lane's row-sum (reg index = col, cndmask tree)
    const float tA0 = (col & 1) ? accA[1] : accA[0];
    const float tA1 = (col & 1) ? accA[3] : accA[2];
    const float tB0 = (col & 1) ? accB[1] : accB[0];
    const float tB1 = (col & 1) ? accB[3] : accB[2];
    const float y = ((col & 2) ? tA1 : tA0) + ((col & 2) ? tB1 : tB0);

    // chain tail: n0 only -> pack -> x write
    const float ni = S * y;
    const float n0 = clamp01(fmaf(r0, T00, fmaf(r1, T10, fmaf(r2, T20, ni))));
    const float nb = dpp_xor1(n0);
    if (xwriter) xh[(s & 1) ^ 1][xslot] = pkrtz(n0, nb);

    const float o0 = r0, o1 = r1, o2 = r2;

    // LDS-only barrier: x write visible; global stores stay in flight
    step_barrier();

    // post-barrier shadow: n1/n2 hidden under next step's x-read latency
    r0 = n0;
    r1 = clamp01(fmaf(o0, T01, fmaf(o1, T11, o2 * T21)));
    r2 = clamp01(fmaf(o0, T02, fmaf(o1, T12, o2 * T22)));
  }
}

} // namespace

extern "C" void kernel_launch(void* const* d_in, const int* in_sizes, int n_in,
                              void* d_out, int out_size, void* d_ws, size_t ws_size,
                              hipStream_t stream)
{
  const float* Rg    = (const float*)d_in[0];
  const float* Tg    = (const float*)d_in[1];
  const float* rho0g = (const float*)d_in[2];
  const float* betag = (const float*)d_in[3];
  float* outg = (float*)d_out;
  sir_meta_kernel<<<NS, BLK, 0, stream>>>(Rg, Tg, rho0g, betag, outg);
}

// Round 20
// 68.113 us; speedup vs baseline: 1.0740x; 1.0740x over previous
//
#include <hip/hip_runtime.h>

namespace {

constexpr int NS = 256;      // samples
constexpr int MP = 128;      // patches
constexpr int TSTEPS = 200;  // timesteps
constexpr int BLK = 512;     // 8 waves -> 2 waves/SIMD (proven optimum)

typedef _Float16 half8 __attribute__((ext_vector_type(8)));
typedef __fp16 h8v __attribute__((ext_vector_type(8)));
typedef float f32x4 __attribute__((ext_vector_type(4)));

__device__ __forceinline__ float4 ldg4(const float* p) {
  return *reinterpret_cast<const float4*>(p);
}
__device__ __forceinline__ float clamp01(float v) {
  return fminf(fmaxf(v, 0.0f), 1.0f);
}
// LDS-visibility barrier that does NOT drain vmcnt (stores stay in flight).
__device__ __forceinline__ void step_barrier() {
  asm volatile("s_waitcnt lgkmcnt(0)" ::: "memory");
  __builtin_amdgcn_s_barrier();
  asm volatile("" ::: "memory");
}
// pack two f32 -> f16x2 (RTZ)
__device__ __forceinline__ unsigned pkrtz(float a, float b) {
  typedef __fp16 h2v __attribute__((ext_vector_type(2)));
  h2v r = __builtin_amdgcn_cvt_pkrtz(a, b);
  return __builtin_bit_cast(unsigned, r);
}
// elementwise f16x8 multiply (4x v_pk_mul_f16)
__device__ __forceinline__ uint4 pkmul4(uint4 a, uint4 b) {
  h8v x = __builtin_bit_cast(h8v, a);
  h8v y = __builtin_bit_cast(h8v, b);
  h8v z = x * y;
  return __builtin_bit_cast(uint4, z);
}
// rotate-add within 16-lane DPP row: 0x121/0x122/0x124/0x128 = ror 1/2/4/8
template <int CTRL>
__device__ __forceinline__ float dpp_radd(float x) {
  int yi = __builtin_amdgcn_update_dpp(0, __float_as_int(x), CTRL, 0xF, 0xF, true);
  return x + __int_as_float(yi);
}
// fetch value from lane^1 (quad_perm [1,0,3,2])
__device__ __forceinline__ float dpp_xor1(float x) {
  int yi = __builtin_amdgcn_update_dpp(0, __float_as_int(x), 0xB1, 0xF, 0xF, true);
  return __int_as_float(yi);
}
// Swizzled uint4 (8 f16) index into f16 Q: 16 quads/row, XOR row-octet
__device__ __forceinline__ int qidx16(int row, int ch) {
  return (row << 4) + (ch ^ ((row >> 3) & 7));
}
__device__ __forceinline__ half8 h8(uint4 v) {
  return __builtin_bit_cast(half8, v);
}

__global__ __launch_bounds__(BLK, 2)
void sir_meta_kernel(const float* __restrict__ Rg,
                     const float* __restrict__ Tg,
                     const float* __restrict__ rho0g,
                     const float* __restrict__ betag,
                     float* __restrict__ outg)
{
  __shared__ __align__(16) float rs[MP];          // 1/rowsum (f32 exact)
  __shared__ __align__(16) unsigned binv16[64];   // beta/neff as f16 pairs
  __shared__ __align__(16) float scr[BLK];
  __shared__ __align__(16) unsigned xh[2][64];    // x as f16 pairs, dbuffered
  __shared__ __align__(16) uint4 q16[MP * 16];    // RAW R in f16 pairs (32KB)
  __shared__ __align__(16) uint4 gh[MP * 16];     // G in f16 pairs (8KB)

  const int tid = threadIdx.x;
  const int n = blockIdx.x;
  const float* __restrict__ Rn = Rg + (size_t)n * MP * MP;

  // ---- S1+S3a fused: stage RAW R as f16 (swizzled) AND row sums -> rs ----
  // Each iter: 32 rows, 16 lanes/row each holding 8 consecutive floats.
  {
    #pragma unroll
    for (int u = 0; u < 4; ++u) {
      const int fi8 = u * BLK + tid;
      const int r = fi8 >> 4, c8 = fi8 & 15;
      float4 lo = ldg4(Rn + r * MP + c8 * 8);
      float4 hi = ldg4(Rn + r * MP + c8 * 8 + 4);
      uint4 w;
      w.x = pkrtz(lo.x, lo.y);
      w.y = pkrtz(lo.z, lo.w);
      w.z = pkrtz(hi.x, hi.y);
      w.w = pkrtz(hi.z, hi.w);
      q16[qidx16(r, c8)] = w;
      // fused row sum: 16-lane DPP reduce of per-lane 8-float partials
      float p = ((lo.x + lo.y) + (lo.z + lo.w)) + ((hi.x + hi.y) + (hi.z + hi.w));
      p = dpp_radd<0x121>(p);
      p = dpp_radd<0x122>(p);
      p = dpp_radd<0x124>(p);
      p = dpp_radd<0x128>(p);
      if ((tid & 15) == 0) rs[r] = 1.0f / p;
    }
  }
  __syncthreads();

  // ---- S2: neff[c] = sum_i Rraw[i][c]*rs[i] (global coalesced, L2-hot) ----
  {
    const int c = tid & 127;
    const int h = tid >> 7;
    float a = 0.0f;
    #pragma unroll 8
    for (int i = 0; i < 32; ++i) {
      const int ig = h * 32 + i;
      a = fmaf(Rn[ig * MP + c], rs[ig], a);
    }
    scr[tid] = a;
  }
  __syncthreads();
  // binv16 pack directly from scr: lane t handles columns 2t, 2t+1
  if (tid < 64) {
    const float beta = betag[n];
    const int c0 = 2 * tid;
    const float s0 = ((scr[c0] + scr[c0 + 128]) + (scr[c0 + 256] + scr[c0 + 384]));
    const float s1 = ((scr[c0 + 1] + scr[c0 + 129]) + (scr[c0 + 257] + scr[c0 + 385]));
    binv16[tid] = pkrtz(beta / s0, beta / s1);
  }
  // initial x as f16 pairs (independent of binv; same barrier covers both)
  if (tid >= 64 && tid < 128) {
    const int t = tid - 64;
    const float* xp = rho0g + ((size_t)n * MP + 2 * t) * 3;
    xh[0][t] = pkrtz(xp[0], xp[3]);
  }
  __syncthreads();

  // ---- S3b: MFMA GEMM. Wave J computes G tiles (I=0..7, J). ----
  // A = raw R tile-I rows; B = binv-scaled tile-J (R17-verified).
  // D (m89): lane(col,kg) reg r = G[16I+4kg+r][16J+col] (pre-scale).
  {
    const int J = tid >> 6;
    const int l = tid & 63;
    const int col = l & 15;
    const int kg = l >> 4;
    const uint4* bnv4 = reinterpret_cast<const uint4*>(binv16);
    uint4 bfj[4];
    #pragma unroll
    for (int c = 0; c < 4; ++c)
      bfj[c] = pkmul4(q16[qidx16(16 * J + col, 4 * c + kg)], bnv4[4 * c + kg]);
    const float rscol = rs[16 * J + col];
    unsigned* ghu = reinterpret_cast<unsigned*>(gh);
    #pragma unroll
    for (int I = 0; I < 8; ++I) {
      const uint4 af0 = q16[qidx16(16 * I + col, 0 + kg)];
      const uint4 af1 = q16[qidx16(16 * I + col, 4 + kg)];
      const uint4 af2 = q16[qidx16(16 * I + col, 8 + kg)];
      const uint4 af3 = q16[qidx16(16 * I + col, 12 + kg)];
      f32x4 a = {0.f, 0.f, 0.f, 0.f};
      a = __builtin_amdgcn_mfma_f32_16x16x32_f16(h8(af0), h8(bfj[0]), a, 0, 0, 0);
      a = __builtin_amdgcn_mfma_f32_16x16x32_f16(h8(af1), h8(bfj[1]), a, 0, 0, 0);
      a = __builtin_amdgcn_mfma_f32_16x16x32_f16(h8(af2), h8(bfj[2]), a, 0, 0, 0);
      a = __builtin_amdgcn_mfma_f32_16x16x32_f16(h8(af3), h8(bfj[3]), a, 0, 0, 0);
      #pragma unroll
      for (int r = 0; r < 4; ++r) {
        const int ROW = 16 * I + 4 * kg + r;
        const float val = a[r] * rs[ROW] * rscol;
        const float nb = dpp_xor1(val);            // neighbor col's scaled val
        if ((col & 1) == 0)
          ghu[ROW * 64 + 8 * J + (col >> 1)] = pkrtz(val, nb);
      }
    }
  }
  __syncthreads();

  // ---- R14 loop (verbatim): wave w owns G rows [16w..16w+16) ----
  const int w = tid >> 6;
  const int l = tid & 63;
  const int col = l & 15;
  const int kg = l >> 4;
  const int jrow = 16 * w + 4 * kg + col;   // this lane's state row (col<4)
  const bool writer = (col < 4);

  uint4 af0 = gh[(16 * w + col) * 16 + 0 + kg];
  uint4 af1 = gh[(16 * w + col) * 16 + 4 + kg];
  uint4 af2 = gh[(16 * w + col) * 16 + 8 + kg];
  uint4 af3 = gh[(16 * w + col) * 16 + 12 + kg];

  const float* Tn = Tg + n * 9;
  const float T00 = Tn[0], T01 = Tn[1], T02 = Tn[2];
  const float T10 = Tn[3], T11 = Tn[4], T12 = Tn[5];
  const float T20 = Tn[6], T21 = Tn[7], T22 = Tn[8];

  float r0 = 0.f, r1 = 0.f, r2 = 0.f;
  if (writer) {
    const float* rp = rho0g + ((size_t)n * MP + jrow) * 3;
    r0 = rp[0]; r1 = rp[1]; r2 = rp[2];
  }

  float4* outp = reinterpret_cast<float4*>(outg) + (size_t)n * TSTEPS * MP + jrow;
  const bool xwriter = writer && ((col & 1) == 0);
  const int xslot = jrow >> 1;              // valid when col even

  for (int s = 0; s < TSTEPS; ++s) {
    // chain head: 4 broadcast uint4 x-reads (4 distinct addrs/wave)
    const uint4* xq4 = reinterpret_cast<const uint4*>(&xh[s & 1][0]);
    const uint4 b0 = xq4[kg];
    const uint4 b1 = xq4[4 + kg];
    const uint4 b2 = xq4[8 + kg];
    const uint4 b3 = xq4[12 + kg];

    // off-chain: emit pre-update state (coalesced 16-lane store per wave)
    const float S = 1.0f - ((r0 + r1) + r2);
    if (writer) *outp = make_float4(S, r0, r1, r2);
    outp += MP;

    // two 2-deep MFMA chains (K = 128 in 32-chunks), summed at select
    f32x4 accA = {0.f, 0.f, 0.f, 0.f};
    f32x4 accB = {0.f, 0.f, 0.f, 0.f};
    accA = __builtin_amdgcn_mfma_f32_16x16x32_f16(h8(af0), h8(b0), accA, 0, 0, 0);
    accB = __builtin_amdgcn_mfma_f32_16x16x32_f16(h8(af1), h8(b1), accB, 0, 0, 0);
    accA = __builtin_amdgcn_mfma_f32_16x16x32_f16(h8(af2), h8(b2), accA, 0, 0, 0);
    accB = __builtin_amdgcn_mfma_f32_16x16x32_f16(h8(af3), h8(b3), accB, 0, 0, 0);

    // static select of this lane's row-sum (reg index = col, cndmask tree)
    const float tA0 = (col & 1) ? accA[1] : accA[0];
    const float tA1 = (col & 1) ? accA[3] : accA[2];
    const float tB0 = (col & 1) ? accB[1] : accB[0];
    const float tB1 = (col & 1) ? accB[3] : accB[2];
    const float y = ((col & 2) ? tA1 : tA0) + ((col & 2) ? tB1 : tB0);

    // state update + clip
    const float ni = S * y;
    const float n0 = clamp01(fmaf(r0, T00, fmaf(r1, T10, fmaf(r2, T20, ni))));
    const float n1 = clamp01(fmaf(r0, T01, fmaf(r1, T11, r2 * T21)));
    const float n2 = clamp01(fmaf(r0, T02, fmaf(r1, T12, r2 * T22)));

    // pack adjacent rows' n0 (col pairs 0-1, 2-3 via quad_perm xor1)
    const float nb = dpp_xor1(n0);
    if (xwriter) xh[(s & 1) ^ 1][xslot] = pkrtz(n0, nb);

    r0 = n0; r1 = n1; r2 = n2;

    // LDS-only barrier: x write visible; global stores stay in flight
    step_barrier();
  }
}

} // namespace

extern "C" void kernel_launch(void* const* d_in, const int* in_sizes, int n_in,
                              void* d_out, int out_size, void* d_ws, size_t ws_size,
                              hipStream_t stream)
{
  const float* Rg    = (const float*)d_in[0];
  const float* Tg    = (const float*)d_in[1];
  const float* rho0g = (const float*)d_in[2];
  const float* betag = (const float*)d_in[3];
  float* outg = (float*)d_out;
  sir_meta_kernel<<<NS, BLK, 0, stream>>>(Rg, Tg, rho0g, betag, outg);
}